// Round 1
// 14994.283 us; speedup vs baseline: 1.5440x; 1.5440x over previous
//
#include <hip/hip_runtime.h>
#include <hip/hip_bf16.h>
#include <stdint.h>
#include <stddef.h>

// Problem constants
#define B_ 32
#define S_ 128
#define T_ 128
#define H_ 512
#define V_ 32000

typedef __bf16 bf16;
typedef __attribute__((ext_vector_type(8))) __bf16 bf16x8;
typedef __attribute__((ext_vector_type(4))) float f32x4;
typedef __attribute__((ext_vector_type(4))) unsigned int u32x4;

#define AS1 __attribute__((address_space(1)))
#define AS3 __attribute__((address_space(3)))

__device__ __forceinline__ void load16_to_lds(const void* g, void* l) {
  __builtin_amdgcn_global_load_lds((AS1 void*)g, (AS3 void*)l, 16, 0, 0);
}

// ---------------------------------------------------------------------------
// Small utility kernels
// ---------------------------------------------------------------------------
__global__ void cvt_bf16(const float* __restrict__ in, bf16* __restrict__ out, int n) {
  int i = (blockIdx.x * 256 + threadIdx.x) * 4;
  if (i + 3 < n) {
    float4 v = *(const float4*)(in + i);
    out[i + 0] = (bf16)v.x; out[i + 1] = (bf16)v.y;
    out[i + 2] = (bf16)v.z; out[i + 3] = (bf16)v.w;
  }
}

// WattnT[n][j] = W_attn[j][n]  (512x512)
__global__ void transpose_cvt(const float* __restrict__ in, bf16* __restrict__ out) {
  int idx = blockIdx.x * 256 + threadIdx.x;
  int n = idx >> 9, j = idx & 511;
  out[idx] = (bf16)in[j * 512 + n];
}

// X[b*T+t][k] = embedding[dec_in(b,t)][k], dec_in = BOS(=1) then targets[:, :-1]
__global__ void gather_emb(const float* __restrict__ emb, const int* __restrict__ tgt,
                           bf16* __restrict__ X) {
  int row = blockIdx.x;
  int b = row >> 7, t = row & 127;
  int tok = (t == 0) ? 1 : tgt[b * T_ + t - 1];
  const float* src = emb + (size_t)tok * H_;
  bf16* dst = X + (size_t)row * H_;
  for (int k = threadIdx.x; k < H_; k += blockDim.x) dst[k] = (bf16)src[k];
}

// Fused+transposed gate weights in k-panel form:
// Wt8[kp][col][kk] (bf16), k = kp*8+kk in [0,1024), col in [0,1536).
//   col = gate*512 + j  (gate 0=r, 1=z, 2=n)
//   k <  512 : ctx input  -> W_ih[gate*512+j][512+k]
//   k >= 512 : h   input  -> W_hh[gate*512+j][k-512]
// (n-gate x/h parts are separated later at the reduction: kp<64 vs kp>=64)
__global__ void build_wt8(const float* __restrict__ Wih, const float* __restrict__ Whh,
                          bf16* __restrict__ out) {
  int o = blockIdx.x * 256 + threadIdx.x;   // 1,572,864 total
  int kk = o & 7;
  int rc = o >> 3;                          // kp*1536 + col
  int col = rc % 1536;
  int kp = rc / 1536;
  int k = kp * 8 + kk;
  int gate = col >> 9, j = col & 511;
  int row = gate * 512 + j;
  float v = (k < 512) ? Wih[(size_t)row * 1024 + 512 + k]
                      : Whh[(size_t)row * 512 + (k - 512)];
  out[o] = (bf16)v;
}

// ---------------------------------------------------------------------------
// Generic bf16 GEMM:  C[M,N](f32) = A[M,K](bf16,lda) @ B^T  with B[N,K](bf16,ldb)
// + optional bias[N].  M%128==0, N%128==0, K%32==0.  grid=(N/128, M/128), 256 thr.
// ---------------------------------------------------------------------------
__launch_bounds__(256)
__global__ void gemm_bt(const bf16* __restrict__ A, int lda,
                        const bf16* __restrict__ Bm, int ldb,
                        float* __restrict__ C, int ldc,
                        const float* __restrict__ bias, int K) {
  __shared__ bf16 As[128 * 32];
  __shared__ bf16 Bs[128 * 32];
  const int m0 = blockIdx.y * 128, n0 = blockIdx.x * 128;
  const int tid = threadIdx.x, lane = tid & 63, wv = tid >> 6;
  const int wm = (wv >> 1) * 64, wn = (wv & 1) * 64;
  f32x4 acc[4][4] = {};

  for (int kt = 0; kt < K; kt += 32) {
    for (int i = 0; i < 2; ++i) {
      int lin = i * 256 + tid;
      int row = lin >> 2;
      int c8  = (lin & 3) * 8;
      const bf16* ga = A  + (size_t)(m0 + row) * lda + kt + c8;
      const bf16* gb = Bm + (size_t)(n0 + row) * ldb + kt + c8;
      load16_to_lds(ga, (char*)As + i * 4096 + wv * 1024);
      load16_to_lds(gb, (char*)Bs + i * 4096 + wv * 1024);
    }
    __builtin_amdgcn_s_waitcnt(0);
    __syncthreads();

    bf16x8 af[4], bfr[4];
    int mrow = lane & 15, qd = lane >> 4;
    for (int i = 0; i < 4; ++i)
      af[i] = *(const bf16x8*)&As[(wm + i * 16 + mrow) * 32 + qd * 8];
    for (int i = 0; i < 4; ++i)
      bfr[i] = *(const bf16x8*)&Bs[(wn + i * 16 + mrow) * 32 + qd * 8];
    for (int mi = 0; mi < 4; ++mi)
      for (int ni = 0; ni < 4; ++ni)
        acc[mi][ni] = __builtin_amdgcn_mfma_f32_16x16x32_bf16(af[mi], bfr[ni], acc[mi][ni], 0, 0, 0);
    __syncthreads();
  }

  int qd = lane >> 4;
  for (int mi = 0; mi < 4; ++mi)
    for (int ni = 0; ni < 4; ++ni) {
      int rbase = m0 + wm + mi * 16 + qd * 4;
      int col   = n0 + wn + ni * 16 + (lane & 15);
      float bv = bias ? bias[col] : 0.f;
      for (int r = 0; r < 4; ++r)
        C[(size_t)(rbase + r) * ldc + col] = acc[mi][ni][r] + bv;
    }
}

// ---------------------------------------------------------------------------
// Per-GROUP barrier (8 blocks), own 128B line per group. Sense-reversing.
// ---------------------------------------------------------------------------
__device__ __forceinline__ void gsync(int* bar, int n) {
  __threadfence();
  __syncthreads();
  if (threadIdx.x == 0) {
    int g = __hip_atomic_load(bar + 1, __ATOMIC_RELAXED, __HIP_MEMORY_SCOPE_AGENT);
    int old = __hip_atomic_fetch_add(bar, 1, __ATOMIC_ACQ_REL, __HIP_MEMORY_SCOPE_AGENT);
    if (old == n - 1) {
      __hip_atomic_store(bar, 0, __ATOMIC_RELAXED, __HIP_MEMORY_SCOPE_AGENT);
      __hip_atomic_fetch_add(bar + 1, 1, __ATOMIC_RELEASE, __HIP_MEMORY_SCOPE_AGENT);
    } else {
      while (__hip_atomic_load(bar + 1, __ATOMIC_ACQUIRE, __HIP_MEMORY_SCOPE_AGENT) == g)
        __builtin_amdgcn_s_sleep(1);
    }
  }
  __syncthreads();
  __threadfence();
}

__device__ __forceinline__ float dot8(bf16x8 w, float4 xa, float4 xb) {
  u32x4 u = __builtin_bit_cast(u32x4, w);
  float s0 = 0.f, s1 = 0.f;
  s0 = fmaf(__builtin_bit_cast(float, u[0] << 16),          xa.x, s0);
  s1 = fmaf(__builtin_bit_cast(float, u[0] & 0xffff0000u),  xa.y, s1);
  s0 = fmaf(__builtin_bit_cast(float, u[1] << 16),          xa.z, s0);
  s1 = fmaf(__builtin_bit_cast(float, u[1] & 0xffff0000u),  xa.w, s1);
  s0 = fmaf(__builtin_bit_cast(float, u[2] << 16),          xb.x, s0);
  s1 = fmaf(__builtin_bit_cast(float, u[2] & 0xffff0000u),  xb.y, s1);
  s0 = fmaf(__builtin_bit_cast(float, u[3] << 16),          xb.z, s0);
  s1 = fmaf(__builtin_bit_cast(float, u[3] & 0xffff0000u),  xb.w, s1);
  return s0 + s1;
}

// ---------------------------------------------------------------------------
// Persistent sequential decoder, v2: 8 blocks per batch (32 independent groups).
// Block (b,g): attention s-rows [g*16,(g+1)*16), gate dims j in [g*64,(g+1)*64).
// All cross-block traffic within a group: 8-wide barrier, plain stores.
// ---------------------------------------------------------------------------
__launch_bounds__(256)
__global__ void seq_decoder2(const float* __restrict__ enc,      // [32][128][512]
                             const float* __restrict__ enc_hid,  // [32][512]
                             const float* __restrict__ P,        // [32][128][512]
                             const float* __restrict__ emb_gx,   // [4096][1536] (incl b_ih)
                             const bf16*  __restrict__ Wt8,      // [128][1536][8]
                             const float* __restrict__ b_hh,     // [1536]
                             float* __restrict__ h_buf,          // [32][512]
                             float* __restrict__ ctx_part,       // [32][8][520]
                             bf16*  __restrict__ x_out,          // [4096][1024]
                             float* __restrict__ h_final,        // [32][512]
                             int* __restrict__ bar) {
  __shared__ float Pq[16 * 520];     // 33,280 B
  __shared__ float Eq[16 * 520];     // 33,280 B
  __shared__ float hs[512];
  __shared__ float xv[1024];         // [ctx | h] f32
  __shared__ float wexp[16];
  __shared__ float dpart[8];
  __shared__ float red[12 * 64];     // [wave][strip][lane]
  __shared__ float bhh_s[192];       // r/z/n slices for this block's 64 dims

  const int tid = threadIdx.x;
  const int b = blockIdx.x >> 3, g = blockIdx.x & 7;
  const int wv = tid >> 6, lane = tid & 63;
  int* barp = bar + b * 32;
  float* ctx_mine = ctx_part + (size_t)(b * 8 + g) * 520;

  // ---- init: stage this block's P/enc slice (f32) + b_hh slice ----
  {
    const float* Psrc = P   + (size_t)(b * 128 + g * 16) * 512;
    const float* Esrc = enc + (size_t)(b * 128 + g * 16) * 512;
    for (int idx = tid * 4; idx < 8192; idx += 1024) {
      int s = idx >> 9, k = idx & 511;
      *(float4*)&Pq[s * 520 + k] = *(const float4*)(Psrc + idx);
      *(float4*)&Eq[s * 520 + k] = *(const float4*)(Esrc + idx);
    }
    if (tid < 192) bhh_s[tid] = b_hh[(tid >> 6) * 512 + g * 64 + (tid & 63)];
  }

  for (int t = 0; t < T_; ++t) {
    const size_t row = (size_t)(b * 128 + t);

    // early emb_gx prefetch (consumed at phase-B end; hides HBM latency)
    float er = 0.f, ez = 0.f, en = 0.f;
    if (tid < 64) {
      const float* eg = emb_gx + row * 1536 + g * 64 + tid;
      er = eg[0]; ez = eg[512]; en = eg[1024];
    }

    // ---- phase A: h -> LDS, energies for 16 s, context partials ----
    {
      const float* hsrc = (t == 0) ? (enc_hid + b * 512) : (h_buf + b * 512);
      *(float2*)&hs[tid * 2] = *(const float2*)(hsrc + tid * 2);
    }
    __syncthreads();
    {
      int s = tid >> 4, i = tid & 15;
      const float* Ps = &Pq[s * 520 + i * 32];
      const float* hp = &hs[i * 32];
      float4 a4 = {0.f, 0.f, 0.f, 0.f};
      for (int c = 0; c < 8; ++c) {
        int c2 = ((c + i) & 7) * 4;
        float4 hv = *(const float4*)(hp + c2);
        float4 pv = *(const float4*)(Ps + c2);
        a4.x += hv.x * pv.x; a4.y += hv.y * pv.y;
        a4.z += hv.z * pv.z; a4.w += hv.w * pv.w;
      }
      float e = (a4.x + a4.y) + (a4.z + a4.w);
      e += __shfl_xor(e, 1); e += __shfl_xor(e, 2);
      e += __shfl_xor(e, 4); e += __shfl_xor(e, 8);
      if (i == 0) wexp[s] = __expf(fminf(e, 80.f));
    }
    __syncthreads();
    {
      float a0 = 0.f, a1 = 0.f;
      for (int s = 0; s < 16; ++s) {
        float w = wexp[s];
        float2 ev = *(const float2*)&Eq[s * 520 + tid * 2];
        a0 = fmaf(w, ev.x, a0); a1 = fmaf(w, ev.y, a1);
      }
      *(float2*)&ctx_mine[tid * 2] = make_float2(a0, a1);
      if (tid == 0) {
        float l = 0.f;
        for (int s = 0; s < 16; ++s) l += wexp[s];
        ctx_mine[512] = l;
      }
    }
    gsync(barp, 8);   // #1: partials visible within group

    // ---- phase B: reduce partials, build x = [ctx | h], gate matvec ----
    {
      if (tid < 8) dpart[tid] = ctx_part[(size_t)(b * 8 + tid) * 520 + 512];
      float a0 = 0.f, a1 = 0.f;
      for (int gg = 0; gg < 8; ++gg) {
        float2 v = *(const float2*)&ctx_part[(size_t)(b * 8 + gg) * 520 + tid * 2];
        a0 += v.x; a1 += v.y;
      }
      __syncthreads();
      float l = ((dpart[0] + dpart[1]) + (dpart[2] + dpart[3])) +
                ((dpart[4] + dpart[5]) + (dpart[6] + dpart[7])) + 1e-35f;
      float c0 = a0 / l, c1 = a1 / l;
      xv[tid * 2] = c0; xv[tid * 2 + 1] = c1;
      xv[512 + tid * 2] = hs[tid * 2]; xv[513 + tid * 2] = hs[tid * 2 + 1];
      if ((tid >> 5) == g) {   // this block owns ctx dims [g*64,(g+1)*64)
        bf16* xo = x_out + row * 1024 + 512 + tid * 2;
        xo[0] = (bf16)c0; xo[1] = (bf16)c1;
      }
    }
    __syncthreads();

    {
      float acc0 = 0.f, acc1 = 0.f, acc2 = 0.f;
      const bf16* w0p = Wt8 + (size_t)(g * 64 + lane) * 8;
      #pragma unroll 4
      for (int kp = wv * 32; kp < wv * 32 + 32; ++kp) {
        const bf16* wrow = w0p + (size_t)kp * (1536 * 8);
        bf16x8 w0 = *(const bf16x8*)(wrow);
        bf16x8 w1 = *(const bf16x8*)(wrow + 512 * 8);
        bf16x8 w2 = *(const bf16x8*)(wrow + 1024 * 8);
        float4 xa = *(const float4*)&xv[kp * 8];
        float4 xb = *(const float4*)&xv[kp * 8 + 4];
        acc0 += dot8(w0, xa, xb);
        acc1 += dot8(w1, xa, xb);
        acc2 += dot8(w2, xa, xb);
      }
      red[(wv * 3 + 0) * 64 + lane] = acc0;
      red[(wv * 3 + 1) * 64 + lane] = acc1;
      red[(wv * 3 + 2) * 64 + lane] = acc2;
    }
    __syncthreads();

    if (tid < 64) {
      float racc = (red[0 * 64 + tid] + red[3 * 64 + tid]) +
                   (red[6 * 64 + tid] + red[9 * 64 + tid]);
      float zacc = (red[1 * 64 + tid] + red[4 * 64 + tid]) +
                   (red[7 * 64 + tid] + red[10 * 64 + tid]);
      float nx   =  red[2 * 64 + tid] + red[5 * 64 + tid];          // kp<64 : ctx part
      float nh   =  red[8 * 64 + tid] + red[11 * 64 + tid];         // kp>=64: h part
      int j = g * 64 + tid;
      float rg = 1.f / (1.f + __expf(-(er + bhh_s[tid] + racc)));
      float zg = 1.f / (1.f + __expf(-(ez + bhh_s[64 + tid] + zacc)));
      float ng = tanhf(en + nx + rg * (bhh_s[128 + tid] + nh));
      float hold = hs[j];
      float hnew = (1.f - zg) * ng + zg * hold;
      h_buf[b * 512 + j] = hnew;
      x_out[row * 1024 + j] = (bf16)hnew;
      if (t == T_ - 1) h_final[b * 512 + j] = hnew;
    }
    gsync(barp, 8);   // #2: h_new visible within group
  }
}

// ---------------------------------------------------------------------------
extern "C" void kernel_launch(void* const* d_in, const int* in_sizes, int n_in,
                              void* d_out, int out_size, void* d_ws, size_t ws_size,
                              hipStream_t stream) {
  (void)in_sizes; (void)n_in; (void)out_size; (void)ws_size;
  const float* enc   = (const float*)d_in[0];
  const float* ehid  = (const float*)d_in[1];
  const int*   tgt   = (const int*)d_in[2];
  const float* emb   = (const float*)d_in[3];
  const float* Wattn = (const float*)d_in[4];
  const float* Wih   = (const float*)d_in[5];
  const float* Whh   = (const float*)d_in[6];
  const float* bih   = (const float*)d_in[7];
  const float* bhh   = (const float*)d_in[8];
  const float* Wout  = (const float*)d_in[9];
  const float* bout  = (const float*)d_in[10];
  float* out = (float*)d_out;

  char* ws = (char*)d_ws;
  float* Pw     = (float*)(ws + 0);            // 8,388,608  B
  float* emb_gx = (float*)(ws + 8388608);      // 25,165,824 B
  bf16*  Xb     = (bf16*) (ws + 33554432);     // 4,194,304  B
  bf16*  Wt8    = (bf16*) (ws + 33554432);     // 3,145,728  B (reuses Xb after emb_gx GEMM)
  bf16*  encb   = (bf16*) (ws + 37748736);     // 4,194,304  B
  float* ctxp   = (float*)(ws + 37748736);     // 532,480    B (reuses encb after P GEMM)
  bf16*  WattnT = (bf16*) (ws + 41943040);     // 524,288    B
  bf16*  Wihb   = (bf16*) (ws + 42467328);     // 3,145,728  B
  bf16*  Woutb  = (bf16*) (ws + 45613056);     // 65,536,000 B
  bf16*  x_out  = (bf16*) (ws + 111149056);    // 8,388,608  B
  float* h_buf  = (float*)(ws + 119537664);    // 65,536     B
  int*   bar    = (int*)  (ws + 119603200);    // 4,096      B (32 groups x 128B)

  hipMemsetAsync(bar, 0, 4096, stream);

  cvt_bf16<<<2048, 256, 0, stream>>>(enc, encb, 2097152);
  cvt_bf16<<<1536, 256, 0, stream>>>(Wih, Wihb, 1572864);
  cvt_bf16<<<32000, 256, 0, stream>>>(Wout, Woutb, 32768000);
  transpose_cvt<<<1024, 256, 0, stream>>>(Wattn, WattnT);
  gather_emb<<<4096, 128, 0, stream>>>(emb, tgt, Xb);

  // P = enc @ W_attn      : [4096,512] x [512,512]
  gemm_bt<<<dim3(4, 32), 256, 0, stream>>>(encb, 512, WattnT, 512, Pw, 512, nullptr, 512);
  // emb_gx = X @ W_ih[:, :512]^T + b_ih : [4096,512] x [1536,512(ld 1024)]
  gemm_bt<<<dim3(12, 32), 256, 0, stream>>>(Xb, 512, Wihb, 1024, emb_gx, 1536, bih, 512);

  // fused/transposed gate weights (after emb_gx GEMM: overlaps Xb region)
  build_wt8<<<6144, 256, 0, stream>>>(Wih, Whh, Wt8);

  seq_decoder2<<<256, 256, 0, stream>>>(enc, ehid, Pw, emb_gx, Wt8, bhh,
                                        h_buf, ctxp, x_out, out + 131072000LL, bar);

  // logits = x_out @ W_out^T + b_out : [4096,1024] x [32000,1024]
  gemm_bt<<<dim3(250, 32), 256, 0, stream>>>(x_out, 1024, Woutb, 1024, out, 32000, bout, 1024);
}